// Round 19
// baseline (888.240 us; speedup 1.0000x reference)
//
#include <hip/hip_runtime.h>
#include <math.h>

#define SEQ    4096
#define NFFT   8192
#define DMODEL 1024
#define ORDER  64
#define CT     512
#define MLPT   256

typedef float2 cf;

// LDS swizzle on complex index: XOR bits [3:1] with bits [6:4].
// Preserves even pairs (bit 0) and float4 (16 B) alignment. Bijective in 4096.
#define ZI(c) ((c) ^ ((((c) >> 4) & 7) << 1))

__device__ __forceinline__ cf cadd(cf a, cf b) { return make_float2(a.x + b.x, a.y + b.y); }
__device__ __forceinline__ cf csub(cf a, cf b) { return make_float2(a.x - b.x, a.y - b.y); }
__device__ __forceinline__ cf cmul(cf a, cf b) { return make_float2(a.x * b.x - a.y * b.y, a.x * b.y + a.y * b.x); }
__device__ __forceinline__ cf cmulj(cf a, cf b) { return make_float2(a.x * b.x + a.y * b.y, a.y * b.x - a.x * b.y); } // a*conj(b)

#define RT2 0.70710678118654752f

template<bool INV> __device__ __forceinline__ cf tw8_1(cf d) {
    if (!INV) return make_float2(RT2 * (d.x + d.y), RT2 * (d.y - d.x));
    else      return make_float2(RT2 * (d.x - d.y), RT2 * (d.y + d.x));
}
template<bool INV> __device__ __forceinline__ cf tw8_2(cf d) {
    if (!INV) return make_float2(d.y, -d.x);
    else      return make_float2(-d.y, d.x);
}
template<bool INV> __device__ __forceinline__ cf tw8_3(cf d) {
    if (!INV) return make_float2(RT2 * (d.y - d.x), -RT2 * (d.x + d.y));
    else      return make_float2(-RT2 * (d.x + d.y), RT2 * (d.x - d.y));
}

template<bool INV>
__device__ __forceinline__ void dft4(cf& x0, cf& x1, cf& x2, cf& x3) {
    cf A = cadd(x0, x2), B = csub(x0, x2);
    cf C = cadd(x1, x3), D = csub(x1, x3);
    x0 = cadd(A, C); x2 = csub(A, C);
    if (!INV) { x1 = make_float2(B.x + D.y, B.y - D.x); x3 = make_float2(B.x - D.y, B.y + D.x); }
    else      { x1 = make_float2(B.x - D.y, B.y + D.x); x3 = make_float2(B.x + D.y, B.y - D.x); }
}

template<bool INV>
__device__ __forceinline__ void dft8(cf v[8]) {
    cf s0 = cadd(v[0], v[4]), s1 = cadd(v[1], v[5]), s2 = cadd(v[2], v[6]), s3 = cadd(v[3], v[7]);
    cf d0 = csub(v[0], v[4]), d1 = csub(v[1], v[5]), d2 = csub(v[2], v[6]), d3 = csub(v[3], v[7]);
    cf t1 = tw8_1<INV>(d1), t2 = tw8_2<INV>(d2), t3 = tw8_3<INV>(d3);
    dft4<INV>(s0, s1, s2, s3);
    dft4<INV>(d0, t1, t2, t3);
    v[0] = s0; v[2] = s1; v[4] = s2; v[6] = s3;
    v[1] = d0; v[3] = t1; v[5] = t2; v[7] = t3;
}

// log-depth twiddle chain (kfft2 pair stages; register-rich kernel)
#define TW_CHAIN(w1, w2, w3, w4, w5, w6, w7) \
    cf w2 = cmul(w1, w1); cf w3 = cmul(w2, w1); cf w4 = cmul(w2, w2); \
    cf w5 = cmul(w3, w2); cf w6 = cmul(w3, w3); cf w7 = cmul(w4, w3);

// ---------------------------------------------------------------------------
// kfft2 pair-butterfly radix-8 stage (256 threads, 4096-pt, b128 LDS ops).
// ---------------------------------------------------------------------------
template<int L, int S>
__device__ __forceinline__ void stage_fwd(float2* z, const cf* __restrict__ tw) {
    int t = threadIdx.x;
    int j0 = 2 * (t & (L / 2 - 1));
    int base = (t / (L / 2)) * (8 * L);
    int c0 = base + j0;
    cf a[8], b[8];
    #pragma unroll
    for (int k = 0; k < 8; k++) {
        float4 p = *(const float4*)&z[ZI(c0 + k * L)];
        a[k] = make_float2(p.x, p.y); b[k] = make_float2(p.z, p.w);
    }
    dft8<false>(a); dft8<false>(b);
    cf wA1 = tw[S * j0], wB1 = tw[S * j0 + S];
    TW_CHAIN(wA1, wA2, wA3, wA4, wA5, wA6, wA7)
    TW_CHAIN(wB1, wB2, wB3, wB4, wB5, wB6, wB7)
    a[1] = cmul(a[1], wA1); b[1] = cmul(b[1], wB1);
    a[2] = cmul(a[2], wA2); b[2] = cmul(b[2], wB2);
    a[3] = cmul(a[3], wA3); b[3] = cmul(b[3], wB3);
    a[4] = cmul(a[4], wA4); b[4] = cmul(b[4], wB4);
    a[5] = cmul(a[5], wA5); b[5] = cmul(b[5], wB5);
    a[6] = cmul(a[6], wA6); b[6] = cmul(b[6], wB6);
    a[7] = cmul(a[7], wA7); b[7] = cmul(b[7], wB7);
    #pragma unroll
    for (int k = 0; k < 8; k++)
        *(float4*)&z[ZI(c0 + k * L)] = make_float4(a[k].x, a[k].y, b[k].x, b[k].y);
    __syncthreads();
}

// ---------------------------------------------------------------------------
// conv single-butterfly radix-8 stages (512 threads, 4096-pt, b64 LDS ops).
// Serial twiddle power chain (register-lean).
// ---------------------------------------------------------------------------
template<int L, int S4>
__device__ __forceinline__ void c4_fwd(float2* z, const cf* __restrict__ tw) {
    int t = threadIdx.x;
    int j = t & (L - 1);
    int c0 = (t / L) * (8 * L) + j;
    cf a[8];
    #pragma unroll
    for (int k = 0; k < 8; k++) a[k] = z[ZI(c0 + k * L)];
    dft8<false>(a);
    cf w1 = tw[S4 * j], w = w1;
    a[1] = cmul(a[1], w);
    #pragma unroll
    for (int k = 2; k < 8; k++) { w = cmul(w, w1); a[k] = cmul(a[k], w); }
    #pragma unroll
    for (int k = 0; k < 8; k++) z[ZI(c0 + k * L)] = a[k];
    __syncthreads();
}

template<int L, int S4>
__device__ __forceinline__ void c4_inv(float2* z, const cf* __restrict__ tw) {
    int t = threadIdx.x;
    int j = t & (L - 1);
    int c0 = (t / L) * (8 * L) + j;
    cf a[8];
    #pragma unroll
    for (int k = 0; k < 8; k++) a[k] = z[ZI(c0 + k * L)];
    cf w1 = tw[S4 * j], w = w1;
    a[1] = cmulj(a[1], w);
    #pragma unroll
    for (int k = 2; k < 8; k++) { w = cmul(w, w1); a[k] = cmulj(a[k], w); }
    dft8<true>(a);
    #pragma unroll
    for (int k = 0; k < 8; k++) z[ZI(c0 + k * L)] = a[k];
    __syncthreads();
}

// ---------------------------------------------------------------------------
// MLP hidden states (Ht[o][l]) + twiddle table init (blocks 0..31).
// ---------------------------------------------------------------------------
__global__ void mlp_kernel(const float* __restrict__ W1, const float* __restrict__ b1,
                           const float* __restrict__ W2, const float* __restrict__ b2,
                           const float* __restrict__ W3, const float* __restrict__ b3,
                           const float* __restrict__ freq, float* __restrict__ Ht,
                           cf* __restrict__ tw) {
    if (blockIdx.x < NFFT / MLPT) {
        int j = blockIdx.x * MLPT + threadIdx.x;
        double ang = (2.0 * M_PI / (double)NFFT) * (double)j;
        tw[j] = make_float2((float)cos(ang), (float)(-sin(ang)));
    }

    int o = threadIdx.x & 63;
    int p = threadIdx.x >> 6;
    int l = blockIdx.x * 4 + p;
    __shared__ float hs[4][ORDER];

    float t   = (float)l / 4095.0f;
    float ang = 1e-4f * (float)(2.0 * M_PI) * (float)l / 4096.0f;
    float z0 = t, z1 = cosf(ang), z2 = -sinf(ang);
    float fo = freq[o];

    float a = z0 * W1[o] + z1 * W1[ORDER + o] + z2 * W1[2 * ORDER + o] + b1[o];
    hs[p][o] = sinf(fo * a);
    __syncthreads();

    a = b2[o];
    #pragma unroll
    for (int i = 0; i < ORDER; i++) a += hs[p][i] * W2[i * ORDER + o];
    float h2 = sinf(fo * a);
    __syncthreads();
    hs[p][o] = h2;
    __syncthreads();

    a = b3[o];
    #pragma unroll
    for (int i = 0; i < ORDER; i++) a += hs[p][i] * W3[i * ORDER + o];
    Ht[o * SEQ + l] = sinf(fo * a);
}

// ---------------------------------------------------------------------------
// kgen2: tiled matmul + modulation: kfil[d][l] = (Ht^T Wout)[l][d] * exp(-t_l*delta_d)
// ---------------------------------------------------------------------------
__global__ __launch_bounds__(MLPT) void kgen2_kernel(const float* __restrict__ Wout,
                                                     const float* __restrict__ Ht,
                                                     float* __restrict__ kfil) {
    __shared__ float Hs[ORDER][68];
    __shared__ float Ws[ORDER][68];
    int t  = threadIdx.x;
    int dt = blockIdx.x & 15, lt = blockIdx.x >> 4;

    #pragma unroll
    for (int r = 0; r < 4; r++) {
        int idx = t + 256 * r;
        int o = idx >> 4, c4 = (idx & 15) * 4;
        *(float4*)&Hs[o][c4] = *(const float4*)&Ht[o * SEQ + lt * 64 + c4];
        *(float4*)&Ws[o][c4] = *(const float4*)&Wout[o * DMODEL + dt * 64 + c4];
    }
    __syncthreads();

    int lq = (t & 15) * 4;
    int dq = (t >> 4) * 4;
    float acc[4][4] = {{0.f}};
    #pragma unroll 8
    for (int o = 0; o < ORDER; o++) {
        float4 h = *(float4*)&Hs[o][lq];
        float4 w = *(float4*)&Ws[o][dq];
        acc[0][0] += w.x * h.x; acc[0][1] += w.x * h.y; acc[0][2] += w.x * h.z; acc[0][3] += w.x * h.w;
        acc[1][0] += w.y * h.x; acc[1][1] += w.y * h.y; acc[1][2] += w.y * h.z; acc[1][3] += w.y * h.w;
        acc[2][0] += w.z * h.x; acc[2][1] += w.z * h.y; acc[2][2] += w.z * h.z; acc[2][3] += w.z * h.w;
        acc[3][0] += w.w * h.x; acc[3][1] += w.w * h.y; acc[3][2] += w.w * h.z; acc[3][3] += w.w * h.w;
    }

    const float MIN_D = -3.0701134573253944f;   // log(.01)/1.5
    const float MAX_D = -15.350567286626971f;   // log(.01)/0.3
    int l0 = lt * 64 + lq;
    #pragma unroll
    for (int di = 0; di < 4; di++) {
        int d = dt * 64 + dq + di;
        float delta = fabsf(MIN_D + (MAX_D - MIN_D) * (float)d / 1023.0f);
        float4 o4;
        o4.x = acc[di][0] * expf(-((float)(l0 + 0) / 4095.0f) * delta);
        o4.y = acc[di][1] * expf(-((float)(l0 + 1) / 4095.0f) * delta);
        o4.z = acc[di][2] * expf(-((float)(l0 + 2) / 4095.0f) * delta);
        o4.w = acc[di][3] * expf(-((float)(l0 + 3) / 4095.0f) * delta);
        *(float4*)&kfil[(size_t)d * SEQ + l0] = o4;
    }
}

// ---------------------------------------------------------------------------
// kfft2: two plain 4096-pt FFTs per channel (round-16 proven, unchanged):
//   rep0: Ke[d][slot] = DFT4096(k)[bin(slot)]        / 8192
//   rep1: Ko[d][slot] = DFT4096(k[n]*W8192^n)[bin]   / 8192
// slot↔bin map identical to conv's 4096 machinery by construction.
// ---------------------------------------------------------------------------
__global__ __launch_bounds__(MLPT) void kfft2_kernel(const float* __restrict__ kfil,
                                                     const cf* __restrict__ tw,
                                                     cf* __restrict__ Ke,
                                                     cf* __restrict__ Ko) {
    int d = blockIdx.x, t = threadIdx.x;
    __shared__ __align__(16) float2 z2[SEQ];   // 32 KiB

    const float2* kf2 = (const float2*)(kfil + (size_t)d * SEQ);
    for (int rep = 0; rep < 2; rep++) {
        if (rep) __syncthreads();             // prior rep's final reads done
        #pragma unroll
        for (int m = 0; m < 8; m++) {
            int s = t + 256 * m;              // complex pair (2s, 2s+1)
            float2 kk = kf2[s];
            if (rep == 0) {
                *(float4*)&z2[ZI(2 * s)] = make_float4(kk.x, 0.f, kk.y, 0.f);
            } else {
                cf w0 = tw[2 * s], w1 = tw[2 * s + 1];
                *(float4*)&z2[ZI(2 * s)] = make_float4(kk.x * w0.x, kk.x * w0.y,
                                                       kk.y * w1.x, kk.y * w1.y);
            }
        }
        __syncthreads();

        stage_fwd<512, 2>(z2, tw);            // W_4096 = tw[2j]
        stage_fwd<64, 16>(z2, tw);            // W_512  = tw[16j]
        stage_fwd<8, 128>(z2, tw);            // W_64   = tw[128j]

        {   // final contiguous dft8 (2 blocks/thread) + scaled coalesced write
            int c0 = 16 * t;
            cf v[16];
            #pragma unroll
            for (int i = 0; i < 8; i++) {
                float4 p = *(const float4*)&z2[ZI(c0 + 2 * i)];
                v[2 * i] = make_float2(p.x, p.y); v[2 * i + 1] = make_float2(p.z, p.w);
            }
            dft8<false>(v); dft8<false>(v + 8);
            const float sc = 1.0f / (float)NFFT;   // folds IDFT 1/4096 and the 1/2
            float4* K4 = (float4*)((rep ? Ko : Ke) + (size_t)d * SEQ + c0);
            #pragma unroll
            for (int i = 0; i < 8; i++)
                K4[i] = make_float4(v[2 * i].x * sc, v[2 * i].y * sc,
                                    v[2 * i + 1].x * sc, v[2 * i + 1].y * sc);
        }
    }
}

// ---------------------------------------------------------------------------
// Main conv: one WG per CHANNEL (grid 1024); loops the 4 batch-pairs so
// Ke[d]/Ko[d] stay L2-hot after the first pair (r16 re-fetched them 4x).
// Body per pair is byte-identical to the round-16 proven kernel:
// even/odd split into two sequential 4096-pt FFT passes in 32 KiB LDS;
// y[n] = pA + conj(W^n)*pB + bias*x. launch_bounds(512,4): VGPR cap 128,
// live ~60 — no spill (r15/r17: tighter wave bounds under-allocate & spill).
// ---------------------------------------------------------------------------
__global__ __launch_bounds__(CT, 4) void conv_kernel(const float* __restrict__ x,
                                                     const float* __restrict__ bias,
                                                     const cf* __restrict__ Ke,
                                                     const cf* __restrict__ Ko,
                                                     const cf* __restrict__ tw,
                                                     float* __restrict__ out) {
    int d = blockIdx.x;
    int t = threadIdx.x;

    __shared__ __align__(16) float2 z[SEQ];   // 32 KiB

    float bd = bias[d];
    const cf* Ked = Ke + (size_t)d * SEQ;
    const cf* Kod = Ko + (size_t)d * SEQ;

    #pragma unroll 1
    for (int pair = 0; pair < 4; ++pair) {
        const float* xa = x + ((size_t)(2 * pair) * DMODEL + d) * SEQ;
        const float* xb = x + ((size_t)(2 * pair + 1) * DMODEL + d) * SEQ;

        cf zr[8], u[8];
        #pragma unroll
        for (int k = 0; k < 8; k++) {
            int n = t + 512 * k;
            zr[k] = make_float2(xa[n], xb[n]);    // z[n] = xa + i*xb
        }

        #pragma unroll 1
        for (int sel = 0; sel < 2; sel++) {
            // ---- stage1 (L=512) from registers ----
            {
                cf a[8];
                if (sel == 0) {
                    #pragma unroll
                    for (int k = 0; k < 8; k++) a[k] = zr[k];
                } else {
                    #pragma unroll
                    for (int k = 0; k < 8; k++) a[k] = cmul(zr[k], tw[t + 512 * k]);
                }
                dft8<false>(a);
                cf w1 = tw[2 * t], w = w1;        // W_4096^t
                a[1] = cmul(a[1], w);
                #pragma unroll
                for (int k = 2; k < 8; k++) { w = cmul(w, w1); a[k] = cmul(a[k], w); }
                #pragma unroll
                for (int k = 0; k < 8; k++) z[ZI(t + 512 * k)] = a[k];
            }
            __syncthreads();

            c4_fwd<64, 16>(z, tw);
            c4_fwd<8, 128>(z, tw);

            // ---- mid: contiguous dft8 + pointwise (Ke/Ko) + inverse dft8 ----
            {
                int c0 = 8 * t;
                cf v[8];
                #pragma unroll
                for (int i = 0; i < 4; i++) {
                    float4 p = *(const float4*)&z[ZI(c0 + 2 * i)];
                    v[2 * i] = make_float2(p.x, p.y); v[2 * i + 1] = make_float2(p.z, p.w);
                }
                dft8<false>(v);
                const float4* K4 = (const float4*)((sel ? Kod : Ked) + c0);
                #pragma unroll
                for (int i = 0; i < 4; i++) {
                    float4 kk = K4[i];
                    v[2 * i]     = cmul(v[2 * i],     make_float2(kk.x, kk.y));
                    v[2 * i + 1] = cmul(v[2 * i + 1], make_float2(kk.z, kk.w));
                }
                dft8<true>(v);
                #pragma unroll
                for (int i = 0; i < 4; i++)
                    *(float4*)&z[ZI(c0 + 2 * i)] = make_float4(v[2 * i].x, v[2 * i].y,
                                                               v[2 * i + 1].x, v[2 * i + 1].y);
            }
            __syncthreads();

            c4_inv<8, 128>(z, tw);
            c4_inv<64, 16>(z, tw);

            // ---- inverse stage1 (L=512) to registers ----
            {
                cf a[8];
                #pragma unroll
                for (int k = 0; k < 8; k++) a[k] = z[ZI(t + 512 * k)];
                cf w1 = tw[2 * t], w = w1;
                a[1] = cmulj(a[1], w);
                #pragma unroll
                for (int k = 2; k < 8; k++) { w = cmul(w, w1); a[k] = cmulj(a[k], w); }
                dft8<true>(a);

                if (sel == 0) {
                    #pragma unroll
                    for (int k = 0; k < 8; k++) u[k] = a[k];   // p (half-scaled)
                } else {
                    float* oa = out + ((size_t)(2 * pair) * DMODEL + d) * SEQ;
                    float* ob = out + ((size_t)(2 * pair + 1) * DMODEL + d) * SEQ;
                    #pragma unroll
                    for (int k = 0; k < 8; k++) {
                        int n = t + 512 * k;
                        cf q = cmulj(a[k], tw[n]);             // q' * conj(W^n)
                        float yx = u[k].x + q.x;
                        float yy = u[k].y + q.y;
                        oa[n] = yx + bd * zr[k].x;
                        ob[n] = yy + bd * zr[k].y;
                    }
                }
            }
            __syncthreads();                  // WAR before next pass's stage1 writes
        }
    }
}

// ---------------------------------------------------------------------------
extern "C" void kernel_launch(void* const* d_in, const int* in_sizes, int n_in,
                              void* d_out, int out_size, void* d_ws, size_t ws_size,
                              hipStream_t stream) {
    (void)in_sizes; (void)n_in; (void)out_size; (void)ws_size;
    const float* x    = (const float*)d_in[0];
    const float* bias = (const float*)d_in[1];
    const float* W1   = (const float*)d_in[2];
    const float* b1   = (const float*)d_in[3];
    const float* W2   = (const float*)d_in[4];
    const float* b2   = (const float*)d_in[5];
    const float* W3   = (const float*)d_in[6];
    const float* b3   = (const float*)d_in[7];
    const float* Wout = (const float*)d_in[8];
    const float* freq = (const float*)d_in[9];
    float* out = (float*)d_out;

    // ws floats: Ht[262144] | tw[8192 cf] | kfil[4194304] | Ke[4096*1024 cf] | Ko[...]
    float* wsf  = (float*)d_ws;
    float* Ht   = wsf;
    cf*    tw   = (cf*)(wsf + 262144);
    float* kfil = wsf + 262144 + 16384;
    cf*    Ke   = (cf*)(wsf + 262144 + 16384 + 4194304);
    cf*    Ko   = (cf*)(wsf + 262144 + 16384 + 4194304 + 8388608);

    hipLaunchKernelGGL(mlp_kernel, dim3(SEQ / 4), dim3(MLPT), 0, stream,
                       W1, b1, W2, b2, W3, b3, freq, Ht, tw);
    hipLaunchKernelGGL(kgen2_kernel, dim3(1024), dim3(MLPT), 0, stream, Wout, Ht, kfil);
    hipLaunchKernelGGL(kfft2_kernel, dim3(DMODEL), dim3(MLPT), 0, stream, kfil, tw, Ke, Ko);
    hipLaunchKernelGGL(conv_kernel, dim3(DMODEL), dim3(CT), 0, stream,
                       x, bias, Ke, Ko, tw, out);
}

// Round 20
// 196.775 us; speedup vs baseline: 4.5140x; 4.5140x over previous
//
#include <hip/hip_runtime.h>
#include <math.h>

#define SEQ    4096
#define NFFT   8192
#define DMODEL 1024
#define ORDER  64
#define CT     512
#define MLPT   256

typedef float2 cf;

// LDS swizzle on complex index: XOR bits [3:1] with bits [6:4].
// Preserves even pairs (bit 0) and float4 (16 B) alignment. Bijective in 4096.
#define ZI(c) ((c) ^ ((((c) >> 4) & 7) << 1))

__device__ __forceinline__ cf cadd(cf a, cf b) { return make_float2(a.x + b.x, a.y + b.y); }
__device__ __forceinline__ cf csub(cf a, cf b) { return make_float2(a.x - b.x, a.y - b.y); }
__device__ __forceinline__ cf cmul(cf a, cf b) { return make_float2(a.x * b.x - a.y * b.y, a.x * b.y + a.y * b.x); }
__device__ __forceinline__ cf cmulj(cf a, cf b) { return make_float2(a.x * b.x + a.y * b.y, a.y * b.x - a.x * b.y); } // a*conj(b)

#define RT2 0.70710678118654752f

template<bool INV> __device__ __forceinline__ cf tw8_1(cf d) {
    if (!INV) return make_float2(RT2 * (d.x + d.y), RT2 * (d.y - d.x));
    else      return make_float2(RT2 * (d.x - d.y), RT2 * (d.y + d.x));
}
template<bool INV> __device__ __forceinline__ cf tw8_2(cf d) {
    if (!INV) return make_float2(d.y, -d.x);
    else      return make_float2(-d.y, d.x);
}
template<bool INV> __device__ __forceinline__ cf tw8_3(cf d) {
    if (!INV) return make_float2(RT2 * (d.y - d.x), -RT2 * (d.x + d.y));
    else      return make_float2(-RT2 * (d.x + d.y), RT2 * (d.x - d.y));
}

template<bool INV>
__device__ __forceinline__ void dft4(cf& x0, cf& x1, cf& x2, cf& x3) {
    cf A = cadd(x0, x2), B = csub(x0, x2);
    cf C = cadd(x1, x3), D = csub(x1, x3);
    x0 = cadd(A, C); x2 = csub(A, C);
    if (!INV) { x1 = make_float2(B.x + D.y, B.y - D.x); x3 = make_float2(B.x - D.y, B.y + D.x); }
    else      { x1 = make_float2(B.x - D.y, B.y + D.x); x3 = make_float2(B.x + D.y, B.y - D.x); }
}

template<bool INV>
__device__ __forceinline__ void dft8(cf v[8]) {
    cf s0 = cadd(v[0], v[4]), s1 = cadd(v[1], v[5]), s2 = cadd(v[2], v[6]), s3 = cadd(v[3], v[7]);
    cf d0 = csub(v[0], v[4]), d1 = csub(v[1], v[5]), d2 = csub(v[2], v[6]), d3 = csub(v[3], v[7]);
    cf t1 = tw8_1<INV>(d1), t2 = tw8_2<INV>(d2), t3 = tw8_3<INV>(d3);
    dft4<INV>(s0, s1, s2, s3);
    dft4<INV>(d0, t1, t2, t3);
    v[0] = s0; v[2] = s1; v[4] = s2; v[6] = s3;
    v[1] = d0; v[3] = t1; v[5] = t2; v[7] = t3;
}

// log-depth twiddle chain (kfft2 pair stages; register-rich kernel)
#define TW_CHAIN(w1, w2, w3, w4, w5, w6, w7) \
    cf w2 = cmul(w1, w1); cf w3 = cmul(w2, w1); cf w4 = cmul(w2, w2); \
    cf w5 = cmul(w3, w2); cf w6 = cmul(w3, w3); cf w7 = cmul(w4, w3);

// ---------------------------------------------------------------------------
// kfft2 pair-butterfly radix-8 stage (256 threads, 4096-pt, b128 LDS ops).
// ---------------------------------------------------------------------------
template<int L, int S>
__device__ __forceinline__ void stage_fwd(float2* z, const cf* __restrict__ tw) {
    int t = threadIdx.x;
    int j0 = 2 * (t & (L / 2 - 1));
    int base = (t / (L / 2)) * (8 * L);
    int c0 = base + j0;
    cf a[8], b[8];
    #pragma unroll
    for (int k = 0; k < 8; k++) {
        float4 p = *(const float4*)&z[ZI(c0 + k * L)];
        a[k] = make_float2(p.x, p.y); b[k] = make_float2(p.z, p.w);
    }
    dft8<false>(a); dft8<false>(b);
    cf wA1 = tw[S * j0], wB1 = tw[S * j0 + S];
    TW_CHAIN(wA1, wA2, wA3, wA4, wA5, wA6, wA7)
    TW_CHAIN(wB1, wB2, wB3, wB4, wB5, wB6, wB7)
    a[1] = cmul(a[1], wA1); b[1] = cmul(b[1], wB1);
    a[2] = cmul(a[2], wA2); b[2] = cmul(b[2], wB2);
    a[3] = cmul(a[3], wA3); b[3] = cmul(b[3], wB3);
    a[4] = cmul(a[4], wA4); b[4] = cmul(b[4], wB4);
    a[5] = cmul(a[5], wA5); b[5] = cmul(b[5], wB5);
    a[6] = cmul(a[6], wA6); b[6] = cmul(b[6], wB6);
    a[7] = cmul(a[7], wA7); b[7] = cmul(b[7], wB7);
    #pragma unroll
    for (int k = 0; k < 8; k++)
        *(float4*)&z[ZI(c0 + k * L)] = make_float4(a[k].x, a[k].y, b[k].x, b[k].y);
    __syncthreads();
}

// ---------------------------------------------------------------------------
// conv single-butterfly radix-8 stages (512 threads, 4096-pt, b64 LDS ops).
// Serial twiddle power chain (register-lean).
// ---------------------------------------------------------------------------
template<int L, int S4>
__device__ __forceinline__ void c4_fwd(float2* z, const cf* __restrict__ tw) {
    int t = threadIdx.x;
    int j = t & (L - 1);
    int c0 = (t / L) * (8 * L) + j;
    cf a[8];
    #pragma unroll
    for (int k = 0; k < 8; k++) a[k] = z[ZI(c0 + k * L)];
    dft8<false>(a);
    cf w1 = tw[S4 * j], w = w1;
    a[1] = cmul(a[1], w);
    #pragma unroll
    for (int k = 2; k < 8; k++) { w = cmul(w, w1); a[k] = cmul(a[k], w); }
    #pragma unroll
    for (int k = 0; k < 8; k++) z[ZI(c0 + k * L)] = a[k];
    __syncthreads();
}

template<int L, int S4>
__device__ __forceinline__ void c4_inv(float2* z, const cf* __restrict__ tw) {
    int t = threadIdx.x;
    int j = t & (L - 1);
    int c0 = (t / L) * (8 * L) + j;
    cf a[8];
    #pragma unroll
    for (int k = 0; k < 8; k++) a[k] = z[ZI(c0 + k * L)];
    cf w1 = tw[S4 * j], w = w1;
    a[1] = cmulj(a[1], w);
    #pragma unroll
    for (int k = 2; k < 8; k++) { w = cmul(w, w1); a[k] = cmulj(a[k], w); }
    dft8<true>(a);
    #pragma unroll
    for (int k = 0; k < 8; k++) z[ZI(c0 + k * L)] = a[k];
    __syncthreads();
}

// ---------------------------------------------------------------------------
// MLP hidden states (Ht[o][l]) + twiddle table init (blocks 0..31).
// ---------------------------------------------------------------------------
__global__ void mlp_kernel(const float* __restrict__ W1, const float* __restrict__ b1,
                           const float* __restrict__ W2, const float* __restrict__ b2,
                           const float* __restrict__ W3, const float* __restrict__ b3,
                           const float* __restrict__ freq, float* __restrict__ Ht,
                           cf* __restrict__ tw) {
    if (blockIdx.x < NFFT / MLPT) {
        int j = blockIdx.x * MLPT + threadIdx.x;
        double ang = (2.0 * M_PI / (double)NFFT) * (double)j;
        tw[j] = make_float2((float)cos(ang), (float)(-sin(ang)));
    }

    int o = threadIdx.x & 63;
    int p = threadIdx.x >> 6;
    int l = blockIdx.x * 4 + p;
    __shared__ float hs[4][ORDER];

    float t   = (float)l / 4095.0f;
    float ang = 1e-4f * (float)(2.0 * M_PI) * (float)l / 4096.0f;
    float z0 = t, z1 = cosf(ang), z2 = -sinf(ang);
    float fo = freq[o];

    float a = z0 * W1[o] + z1 * W1[ORDER + o] + z2 * W1[2 * ORDER + o] + b1[o];
    hs[p][o] = sinf(fo * a);
    __syncthreads();

    a = b2[o];
    #pragma unroll
    for (int i = 0; i < ORDER; i++) a += hs[p][i] * W2[i * ORDER + o];
    float h2 = sinf(fo * a);
    __syncthreads();
    hs[p][o] = h2;
    __syncthreads();

    a = b3[o];
    #pragma unroll
    for (int i = 0; i < ORDER; i++) a += hs[p][i] * W3[i * ORDER + o];
    Ht[o * SEQ + l] = sinf(fo * a);
}

// ---------------------------------------------------------------------------
// kgen2: tiled matmul + modulation: kfil[d][l] = (Ht^T Wout)[l][d] * exp(-t_l*delta_d)
// ---------------------------------------------------------------------------
__global__ __launch_bounds__(MLPT) void kgen2_kernel(const float* __restrict__ Wout,
                                                     const float* __restrict__ Ht,
                                                     float* __restrict__ kfil) {
    __shared__ float Hs[ORDER][68];
    __shared__ float Ws[ORDER][68];
    int t  = threadIdx.x;
    int dt = blockIdx.x & 15, lt = blockIdx.x >> 4;

    #pragma unroll
    for (int r = 0; r < 4; r++) {
        int idx = t + 256 * r;
        int o = idx >> 4, c4 = (idx & 15) * 4;
        *(float4*)&Hs[o][c4] = *(const float4*)&Ht[o * SEQ + lt * 64 + c4];
        *(float4*)&Ws[o][c4] = *(const float4*)&Wout[o * DMODEL + dt * 64 + c4];
    }
    __syncthreads();

    int lq = (t & 15) * 4;
    int dq = (t >> 4) * 4;
    float acc[4][4] = {{0.f}};
    #pragma unroll 8
    for (int o = 0; o < ORDER; o++) {
        float4 h = *(float4*)&Hs[o][lq];
        float4 w = *(float4*)&Ws[o][dq];
        acc[0][0] += w.x * h.x; acc[0][1] += w.x * h.y; acc[0][2] += w.x * h.z; acc[0][3] += w.x * h.w;
        acc[1][0] += w.y * h.x; acc[1][1] += w.y * h.y; acc[1][2] += w.y * h.z; acc[1][3] += w.y * h.w;
        acc[2][0] += w.z * h.x; acc[2][1] += w.z * h.y; acc[2][2] += w.z * h.z; acc[2][3] += w.z * h.w;
        acc[3][0] += w.w * h.x; acc[3][1] += w.w * h.y; acc[3][2] += w.w * h.z; acc[3][3] += w.w * h.w;
    }

    const float MIN_D = -3.0701134573253944f;   // log(.01)/1.5
    const float MAX_D = -15.350567286626971f;   // log(.01)/0.3
    int l0 = lt * 64 + lq;
    #pragma unroll
    for (int di = 0; di < 4; di++) {
        int d = dt * 64 + dq + di;
        float delta = fabsf(MIN_D + (MAX_D - MIN_D) * (float)d / 1023.0f);
        float4 o4;
        o4.x = acc[di][0] * expf(-((float)(l0 + 0) / 4095.0f) * delta);
        o4.y = acc[di][1] * expf(-((float)(l0 + 1) / 4095.0f) * delta);
        o4.z = acc[di][2] * expf(-((float)(l0 + 2) / 4095.0f) * delta);
        o4.w = acc[di][3] * expf(-((float)(l0 + 3) / 4095.0f) * delta);
        *(float4*)&kfil[(size_t)d * SEQ + l0] = o4;
    }
}

// ---------------------------------------------------------------------------
// kfft2: two plain 4096-pt FFTs per channel (no untangle, coalesced output):
//   rep0: Ke[d][slot] = DFT4096(k)[bin(slot)]        / 8192
//   rep1: Ko[d][slot] = DFT4096(k[n]*W8192^n)[bin]   / 8192
// slot↔bin map identical to conv's 4096 machinery by construction.
// ---------------------------------------------------------------------------
__global__ __launch_bounds__(MLPT) void kfft2_kernel(const float* __restrict__ kfil,
                                                     const cf* __restrict__ tw,
                                                     cf* __restrict__ Ke,
                                                     cf* __restrict__ Ko) {
    int d = blockIdx.x, t = threadIdx.x;
    __shared__ __align__(16) float2 z2[SEQ];   // 32 KiB

    const float2* kf2 = (const float2*)(kfil + (size_t)d * SEQ);
    for (int rep = 0; rep < 2; rep++) {
        if (rep) __syncthreads();             // prior rep's final reads done
        #pragma unroll
        for (int m = 0; m < 8; m++) {
            int s = t + 256 * m;              // complex pair (2s, 2s+1)
            float2 kk = kf2[s];
            if (rep == 0) {
                *(float4*)&z2[ZI(2 * s)] = make_float4(kk.x, 0.f, kk.y, 0.f);
            } else {
                cf w0 = tw[2 * s], w1 = tw[2 * s + 1];
                *(float4*)&z2[ZI(2 * s)] = make_float4(kk.x * w0.x, kk.x * w0.y,
                                                       kk.y * w1.x, kk.y * w1.y);
            }
        }
        __syncthreads();

        stage_fwd<512, 2>(z2, tw);            // W_4096 = tw[2j]
        stage_fwd<64, 16>(z2, tw);            // W_512  = tw[16j]
        stage_fwd<8, 128>(z2, tw);            // W_64   = tw[128j]

        {   // final contiguous dft8 (2 blocks/thread) + scaled coalesced write
            int c0 = 16 * t;
            cf v[16];
            #pragma unroll
            for (int i = 0; i < 8; i++) {
                float4 p = *(const float4*)&z2[ZI(c0 + 2 * i)];
                v[2 * i] = make_float2(p.x, p.y); v[2 * i + 1] = make_float2(p.z, p.w);
            }
            dft8<false>(v); dft8<false>(v + 8);
            const float sc = 1.0f / (float)NFFT;   // folds IDFT 1/4096 and the 1/2
            float4* K4 = (float4*)((rep ? Ko : Ke) + (size_t)d * SEQ + c0);
            #pragma unroll
            for (int i = 0; i < 8; i++)
                K4[i] = make_float4(v[2 * i].x * sc, v[2 * i].y * sc,
                                    v[2 * i + 1].x * sc, v[2 * i + 1].y * sc);
        }
    }
}

// ---------------------------------------------------------------------------
// Main conv: one WG per (channel, batch-pair); 512 threads, 32 KiB LDS.
// Even/odd split of the 8192-pt zero-padded conv into two sequential 4096-pt
// FFT passes: p = IFFT(FFT(z)*Ke); q' = IFFT(FFT(z*W^n)*Ko);
// y[n] = p + q'*conj(W^n)  (scales folded into Ke/Ko).
// launch_bounds(512,4): VGPR cap 128 — live state ~60 regs, VGPR_Count 64,
// no spill. This config is the proven stable optimum (round 16: 197.7 µs);
// r17 (512,6)=40 VGPR spill, r18 interleave=64 KiB LDS + spill,
// r19 pair-loop=loop-carried spill all regressed.
// ---------------------------------------------------------------------------
__global__ __launch_bounds__(CT, 4) void conv_kernel(const float* __restrict__ x,
                                                     const float* __restrict__ bias,
                                                     const cf* __restrict__ Ke,
                                                     const cf* __restrict__ Ko,
                                                     const cf* __restrict__ tw,
                                                     float* __restrict__ out) {
    int wg = blockIdx.x;
    int d = wg & (DMODEL - 1);
    int pair = wg >> 10;
    int t = threadIdx.x;

    const float* xa = x + ((size_t)(2 * pair) * DMODEL + d) * SEQ;
    const float* xb = x + ((size_t)(2 * pair + 1) * DMODEL + d) * SEQ;

    __shared__ __align__(16) float2 z[SEQ];   // 32 KiB

    cf zr[8], u[8];
    #pragma unroll
    for (int k = 0; k < 8; k++) {
        int n = t + 512 * k;
        zr[k] = make_float2(xa[n], xb[n]);    // z[n] = xa + i*xb
    }

    for (int sel = 0; sel < 2; sel++) {
        // ---- stage1 (L=512) from registers ----
        {
            cf a[8];
            if (sel == 0) {
                #pragma unroll
                for (int k = 0; k < 8; k++) a[k] = zr[k];
            } else {
                #pragma unroll
                for (int k = 0; k < 8; k++) a[k] = cmul(zr[k], tw[t + 512 * k]);
            }
            dft8<false>(a);
            cf w1 = tw[2 * t], w = w1;        // W_4096^t
            a[1] = cmul(a[1], w);
            #pragma unroll
            for (int k = 2; k < 8; k++) { w = cmul(w, w1); a[k] = cmul(a[k], w); }
            #pragma unroll
            for (int k = 0; k < 8; k++) z[ZI(t + 512 * k)] = a[k];
        }
        __syncthreads();

        c4_fwd<64, 16>(z, tw);
        c4_fwd<8, 128>(z, tw);

        // ---- mid: contiguous dft8 + pointwise (Ke/Ko) + inverse dft8 ----
        {
            int c0 = 8 * t;
            cf v[8];
            #pragma unroll
            for (int i = 0; i < 4; i++) {
                float4 p = *(const float4*)&z[ZI(c0 + 2 * i)];
                v[2 * i] = make_float2(p.x, p.y); v[2 * i + 1] = make_float2(p.z, p.w);
            }
            dft8<false>(v);
            const float4* K4 = (const float4*)((sel ? Ko : Ke) + (size_t)d * SEQ + c0);
            #pragma unroll
            for (int i = 0; i < 4; i++) {
                float4 kk = K4[i];
                v[2 * i]     = cmul(v[2 * i],     make_float2(kk.x, kk.y));
                v[2 * i + 1] = cmul(v[2 * i + 1], make_float2(kk.z, kk.w));
            }
            dft8<true>(v);
            #pragma unroll
            for (int i = 0; i < 4; i++)
                *(float4*)&z[ZI(c0 + 2 * i)] = make_float4(v[2 * i].x, v[2 * i].y,
                                                           v[2 * i + 1].x, v[2 * i + 1].y);
        }
        __syncthreads();

        c4_inv<8, 128>(z, tw);
        c4_inv<64, 16>(z, tw);

        // ---- inverse stage1 (L=512) to registers ----
        {
            cf a[8];
            #pragma unroll
            for (int k = 0; k < 8; k++) a[k] = z[ZI(t + 512 * k)];
            cf w1 = tw[2 * t], w = w1;
            a[1] = cmulj(a[1], w);
            #pragma unroll
            for (int k = 2; k < 8; k++) { w = cmul(w, w1); a[k] = cmulj(a[k], w); }
            dft8<true>(a);

            if (sel == 0) {
                #pragma unroll
                for (int k = 0; k < 8; k++) u[k] = a[k];   // p (half-scaled)
            } else {
                float bd = bias[d];
                float* oa = out + ((size_t)(2 * pair) * DMODEL + d) * SEQ;
                float* ob = out + ((size_t)(2 * pair + 1) * DMODEL + d) * SEQ;
                #pragma unroll
                for (int k = 0; k < 8; k++) {
                    int n = t + 512 * k;
                    cf q = cmulj(a[k], tw[n]);             // q' * conj(W^n)
                    float yx = u[k].x + q.x;
                    float yy = u[k].y + q.y;
                    oa[n] = yx + bd * zr[k].x;
                    ob[n] = yy + bd * zr[k].y;
                }
            }
        }
        __syncthreads();                      // WAR before next pass's stage1 writes
    }
}

// ---------------------------------------------------------------------------
extern "C" void kernel_launch(void* const* d_in, const int* in_sizes, int n_in,
                              void* d_out, int out_size, void* d_ws, size_t ws_size,
                              hipStream_t stream) {
    (void)in_sizes; (void)n_in; (void)out_size; (void)ws_size;
    const float* x    = (const float*)d_in[0];
    const float* bias = (const float*)d_in[1];
    const float* W1   = (const float*)d_in[2];
    const float* b1   = (const float*)d_in[3];
    const float* W2   = (const float*)d_in[4];
    const float* b2   = (const float*)d_in[5];
    const float* W3   = (const float*)d_in[6];
    const float* b3   = (const float*)d_in[7];
    const float* Wout = (const float*)d_in[8];
    const float* freq = (const float*)d_in[9];
    float* out = (float*)d_out;

    // ws floats: Ht[262144] | tw[8192 cf] | kfil[4194304] | Ke[4096*1024 cf] | Ko[...]
    float* wsf  = (float*)d_ws;
    float* Ht   = wsf;
    cf*    tw   = (cf*)(wsf + 262144);
    float* kfil = wsf + 262144 + 16384;
    cf*    Ke   = (cf*)(wsf + 262144 + 16384 + 4194304);
    cf*    Ko   = (cf*)(wsf + 262144 + 16384 + 4194304 + 8388608);

    hipLaunchKernelGGL(mlp_kernel, dim3(SEQ / 4), dim3(MLPT), 0, stream,
                       W1, b1, W2, b2, W3, b3, freq, Ht, tw);
    hipLaunchKernelGGL(kgen2_kernel, dim3(1024), dim3(MLPT), 0, stream, Wout, Ht, kfil);
    hipLaunchKernelGGL(kfft2_kernel, dim3(DMODEL), dim3(MLPT), 0, stream, kfil, tw, Ke, Ko);
    hipLaunchKernelGGL(conv_kernel, dim3(DMODEL * 4), dim3(CT), 0, stream,
                       x, bias, Ke, Ko, tw, out);
}